// Round 1
// baseline (55.039 us; speedup 1.0000x reference)
//
#include <hip/hip_runtime.h>
#include <hip/hip_bf16.h>

// QuantumLLPModel: probs[b, j<10] of a 14-qubit product state.
// Only the 4 least-significant qubits (cols 10..13) matter: the common
// factor prod_{i<10} p0[b,i] cancels under the final normalization.
// p0 = (1+cos(pi*x+p))/2, p1 = (1-cos(pi*x+p))/2 -- one cos per qubit.

#define NQ 14
#define NOUT 10

__global__ __launch_bounds__(256) void quantum_llp_kernel(
    const float* __restrict__ x,       // [B, 14]
    const float* __restrict__ params,  // [14]
    float* __restrict__ out,           // [B, 10]
    int B)
{
    int b = blockIdx.x * blockDim.x + threadIdx.x;
    if (b >= B) return;

    const float PI = 3.14159265358979323846f;

    // params[10..13] broadcast via scalar cache; x row loads hit L1/L2.
    float p0v[4], p1v[4];
#pragma unroll
    for (int k = 0; k < 4; ++k) {
        int i = NQ - 4 + k;  // qubits 10..13
        float ang = PI * x[b * NQ + i] + params[i];
        float c = __cosf(ang);
        p0v[k] = 0.5f * (1.0f + c);  // cos^2(ang/2)
        p1v[k] = 0.5f * (1.0f - c);  // sin^2(ang/2)
    }

    // j bits: bit3 -> qubit10, bit2 -> qubit11, bit1 -> qubit12, bit0 -> qubit13
    float q[NOUT];
    float s = 0.0f;
#pragma unroll
    for (int j = 0; j < NOUT; ++j) {
        float v = (((j >> 3) & 1) ? p1v[0] : p0v[0])
                * (((j >> 2) & 1) ? p1v[1] : p0v[1])
                * (((j >> 1) & 1) ? p1v[2] : p0v[2])
                * (( j       & 1) ? p1v[3] : p0v[3]);
        q[j] = v;
        s += v;
    }

    float inv = 1.0f / s;  // s > 0: p0+p1 = 1 per qubit, so not all q vanish
#pragma unroll
    for (int j = 0; j < NOUT; ++j) {
        out[b * NOUT + j] = q[j] * inv;
    }
}

extern "C" void kernel_launch(void* const* d_in, const int* in_sizes, int n_in,
                              void* d_out, int out_size, void* d_ws, size_t ws_size,
                              hipStream_t stream) {
    const float* x      = (const float*)d_in[0];  // [B,14] f32
    const float* params = (const float*)d_in[1];  // [14]   f32
    float* out          = (float*)d_out;          // [B,10] f32

    int B = in_sizes[0] / NQ;  // 8192
    int block = 256;
    int grid = (B + block - 1) / block;
    quantum_llp_kernel<<<grid, block, 0, stream>>>(x, params, out, B);
}